// Round 4
// baseline (717.767 us; speedup 1.0000x reference)
//
#include <hip/hip_runtime.h>

// NearestEmbed (VQ argmin + gather), MI355X gfx950.  Round 4.
// x: (B=64, D=64, H=32, W=32) fp32 ; emb: (D=64, K=512) fp32
// out0: quant (B,D,H,W) fp32 ; out1: argmin (B,H,W) as fp32 values.
//
// R4 changes vs R3 (post-mortem: VGPR=48 proved xv[64] never lived in regs;
// rematerialized loads kept VALUBusy at 68%):
//  * x row staged in LDS ([d][row], 16 KB/block); hot loop reads 1 ds_read_b32
//    per d-step (stride-1, conflict-free). Per-thread state = 16 acc floats ->
//    no spill pressure at all.
//  * Packed fp32: codes paired into float2, __builtin_elementwise_fma ->
//    v_pk_fma_f32 (e-pair = consecutive SGPRs from s_load; x splat via op_sel).
//    Halves the VALU instruction count (floor 27.3 -> 13.7 us if full-rate).
//  * 1024 blocks x 256 thr = 4 blocks/CU, 4 waves/SIMD for latency hiding.
//  * emb scalar path kept: wave-uniform addresses -> s_load + SGPR operands.

constexpr int D  = 64;
constexpr int K  = 512;
constexpr int HW = 1024;       // 32*32
constexpr int RB = 64;         // rows per block

typedef float v2 __attribute__((ext_vector_type(2)));

__global__ __launch_bounds__(256, 4) void vq_argmin_kernel(
    const float* __restrict__ x,
    const float* __restrict__ emb,
    float* __restrict__ out_q,
    float* __restrict__ out_idx)
{
    __shared__ float xs[D * RB];       // 16 KB, layout [d][row]
    __shared__ float e2s[K];           // 2 KB
    __shared__ float mb[4][RB];
    __shared__ int   mi[4][RB];
    __shared__ int   kfin[RB];

    const int tid  = threadIdx.x;
    const int lane = tid & 63;                                   // block-local row
    const int wv   = __builtin_amdgcn_readfirstlane(tid >> 6);   // code quarter 0..3
    const int r0   = blockIdx.x * RB;                            // first row of block
    const int b    = r0 >> 10;                                   // batch (blocks never straddle)
    const int n0   = r0 & 1023;                                  // spatial base

    // --- ||e_k||^2 (codes tid, tid+256): coalesced, also warms L2 for s_loads ---
    for (int k = tid; k < K; k += 256) {
        float s = 0.f;
        #pragma unroll 16
        for (int d = 0; d < D; ++d) { float v = emb[d * K + k]; s = fmaf(v, v, s); }
        e2s[k] = s;
    }

    // --- stage x tile: [d][row], 256 threads x 16 iters, fully coalesced ---
    for (int i = tid; i < D * RB; i += 256) {
        int d = i >> 6, row = i & 63;
        xs[i] = x[(size_t)(b * D + d) * HW + n0 + row];
    }
    __syncthreads();

    // --- this wave scans its 128-code quarter in 8 chunks of 16 codes ---
    float best = 3.4e38f;
    int   bidx = 0;
    const int kq = wv * 128;

    for (int ch = 0; ch < 8; ++ch) {                 // rolled: body ~ code-size safe
        const int kbase = kq + ch * 16;
        v2 acc[8];
        #pragma unroll
        for (int p = 0; p < 8; ++p) acc[p] = (v2){0.f, 0.f};

        #pragma unroll
        for (int d = 0; d < D; ++d) {
            const float xd = xs[d * RB + lane];       // ds_read_b32, stride-1
            const v2 xsp = {xd, xd};                  // splat (op_sel, free)
            const v2* ep = (const v2*)(emb + d * K + kbase);   // wave-uniform -> s_load
            #pragma unroll
            for (int p = 0; p < 8; ++p)
                acc[p] = __builtin_elementwise_fma(xsp, ep[p], acc[p]);  // v_pk_fma_f32
        }

        #pragma unroll
        for (int p = 0; p < 8; ++p) {
            v2 e2p = *(const v2*)&e2s[kbase + 2 * p];            // LDS broadcast
            v2 s   = __builtin_elementwise_fma((v2){-2.f, -2.f}, acc[p], e2p);
            const int k0 = kbase + 2 * p;
            if (s.x < best) { best = s.x; bidx = k0; }           // strict <: first-index
            if (s.y < best) { best = s.y; bidx = k0 + 1; }
        }
    }

    // --- merge 4 quarters per row (ascending wv => lowest index wins ties) ---
    mb[wv][lane] = best; mi[wv][lane] = bidx;
    __syncthreads();

    if (tid < RB) {
        float bb = mb[0][tid]; int bi = mi[0][tid];
        #pragma unroll
        for (int w = 1; w < 4; ++w) {
            float ob = mb[w][tid]; int oi = mi[w][tid];
            if (ob < bb) { bb = ob; bi = oi; }
        }
        kfin[tid] = bi;
        __builtin_nontemporal_store((float)bi, &out_idx[r0 + tid]);
    }
    __syncthreads();

    // --- epilogue: gather + coalesced nontemporal stores ---
    for (int i = tid; i < D * RB; i += 256) {
        int d = i >> 6, row = i & 63;
        __builtin_nontemporal_store(emb[d * K + kfin[row]],
                                    &out_q[(size_t)(b * D + d) * HW + n0 + row]);
    }
}

extern "C" void kernel_launch(void* const* d_in, const int* in_sizes, int n_in,
                              void* d_out, int out_size, void* d_ws, size_t ws_size,
                              hipStream_t stream)
{
    const float* x   = (const float*)d_in[0];   // 4194304 floats
    const float* emb = (const float*)d_in[1];   // 32768 floats

    float* out_q   = (float*)d_out;                     // 4194304 floats
    float* out_idx = out_q + (size_t)64 * 64 * 1024;    // 65536 floats

    // 65536 rows / 64 rows-per-block = 1024 blocks of 256 threads
    // (4 code-quarters per row inside the block) -> 4 blocks/CU, 4 waves/SIMD.
    vq_argmin_kernel<<<1024, 256, 0, stream>>>(x, emb, out_q, out_idx);
}

// Round 5
// 171.361 us; speedup vs baseline: 4.1886x; 4.1886x over previous
//
#include <hip/hip_runtime.h>

// NearestEmbed (VQ argmin + gather), MI355X gfx950.  Round 5.
// x: (B=64, D=64, H=32, W=32) fp32 ; emb: (D=64, K=512) fp32
// out0: quant (B,D,H,W) fp32 ; out1: argmin (B,H,W) as fp32 values.
//
// R5 vs R4 post-mortem: R4's FETCH=1.1GB == threads*(d,ch)*8B proved the
// `v2 acc[8]` alloca was left in scratch (SROA failure on ext-vector array);
// every pk-fma did a scratch round-trip. Fix: 16 *named* v2 accumulators
// (macro-generated, cannot be demoted). Everything else keeps the proven
// pieces: LDS-staged x ([d][row], stride-1 conflict-free, immediate ds
// offsets), wave-uniform emb loads -> s_load with code-pairs in consecutive
// SGPRs (natural v_pk_fma_f32 B operand; x splat via op_sel), nontemporal
// coalesced stores (R3: WRITE=16.6MB ideal).
// Floor: 1.07e9 pk-fma / 1024 SIMD * 2cy = 13.7 us.

constexpr int D  = 64;
constexpr int K  = 512;
constexpr int HW = 1024;       // 32*32
constexpr int RB = 64;         // rows per block

typedef float v2 __attribute__((ext_vector_type(2)));
typedef float f4 __attribute__((ext_vector_type(4)));

__global__ __launch_bounds__(256, 4) void vq_argmin_kernel(
    const float* __restrict__ x,
    const float* __restrict__ emb,
    float* __restrict__ out_q,
    float* __restrict__ out_idx)
{
    __shared__ float xs[D * RB];       // 16 KB, [d][row]
    __shared__ float e2s[K];           // 2 KB
    __shared__ float mb[4][RB];
    __shared__ int   mi[4][RB];
    __shared__ int   kfin[RB];

    const int tid  = threadIdx.x;
    const int lane = tid & 63;                                   // block-local row
    const int wv   = __builtin_amdgcn_readfirstlane(tid >> 6);   // code quarter 0..3
    const int r0   = blockIdx.x * RB;
    const int b    = r0 >> 10;                                   // batch (no straddle)
    const int n0   = r0 & 1023;                                  // spatial base

    // --- ||e_k||^2 (coalesced; warms L2 for the scalar emb loads) ---
    for (int k = tid; k < K; k += 256) {
        float s = 0.f;
        #pragma unroll 16
        for (int d = 0; d < D; ++d) { float v = emb[d * K + k]; s = fmaf(v, v, s); }
        e2s[k] = s;
    }

    // --- stage x tile [d][row] via float4 (n0 is 64-aligned => 16B-aligned) ---
    {
        const f4* xv4 = (const f4*)(x + (size_t)b * D * HW + n0);
        f4* xs4 = (f4*)xs;
        #pragma unroll
        for (int i = tid; i < D * RB / 4; i += 256) {    // 4 iters
            int d = i >> 4, c = i & 15;                  // 16 f4 per d-plane
            xs4[i] = xv4[d * (HW / 4) + c];
        }
    }
    __syncthreads();

    // --- this wave scans its 128-code quarter in 4 chunks of 32 codes ---
    float best = 3.4e38f;
    int   bidx = 0;
    const int kq = wv * 128;

    for (int ch = 0; ch < 4; ++ch) {
        const int k0 = kq + ch * 32;

        // 16 NAMED v2 accumulators — no array, no alloca, no scratch.
        v2 a0={0.f,0.f}, a1={0.f,0.f}, a2={0.f,0.f}, a3={0.f,0.f},
           a4={0.f,0.f}, a5={0.f,0.f}, a6={0.f,0.f}, a7={0.f,0.f},
           a8={0.f,0.f}, a9={0.f,0.f}, a10={0.f,0.f}, a11={0.f,0.f},
           a12={0.f,0.f}, a13={0.f,0.f}, a14={0.f,0.f}, a15={0.f,0.f};

        const float* eb = emb + k0;        // wave-uniform
        const float* xp = xs + lane;

        #pragma unroll 4
        for (int d = 0; d < D; ++d) {
            const float xd = xp[d * RB];                  // ds_read_b32, stride-1
            const v2 xsp = {xd, xd};                      // splat (op_sel)
            const v2* ev = (const v2*)(eb + d * K);       // uniform -> s_load pairs
#define PKF(p) a##p = __builtin_elementwise_fma(xsp, ev[p], a##p);
            PKF(0) PKF(1) PKF(2)  PKF(3)  PKF(4)  PKF(5)  PKF(6)  PKF(7)
            PKF(8) PKF(9) PKF(10) PKF(11) PKF(12) PKF(13) PKF(14) PKF(15)
#undef PKF
        }

        // scores: -2*dot + ||e||^2 ; ascending k order => first-index ties
#define SCORE(p) { \
            float sx = fmaf(-2.f, a##p.x, e2s[k0 + 2*(p)]); \
            float sy = fmaf(-2.f, a##p.y, e2s[k0 + 2*(p) + 1]); \
            if (sx < best) { best = sx; bidx = k0 + 2*(p); } \
            if (sy < best) { best = sy; bidx = k0 + 2*(p) + 1; } }
        SCORE(0) SCORE(1) SCORE(2)  SCORE(3)  SCORE(4)  SCORE(5)  SCORE(6)  SCORE(7)
        SCORE(8) SCORE(9) SCORE(10) SCORE(11) SCORE(12) SCORE(13) SCORE(14) SCORE(15)
#undef SCORE
    }

    // --- 4-way quarter merge per row (ascending wv => lowest index on ties) ---
    mb[wv][lane] = best; mi[wv][lane] = bidx;
    __syncthreads();

    if (tid < RB) {
        float bb = mb[0][tid]; int bi = mi[0][tid];
        #pragma unroll
        for (int w = 1; w < 4; ++w) {
            float ob = mb[w][tid]; int oi = mi[w][tid];
            if (ob < bb) { bb = ob; bi = oi; }
        }
        kfin[tid] = bi;
        __builtin_nontemporal_store((float)bi, &out_idx[r0 + tid]);
    }
    __syncthreads();

    // --- epilogue: gather (emb L2-hot) + coalesced nontemporal stores ---
    for (int i = tid; i < D * RB; i += 256) {             // 16 iters
        int d = i >> 6, row = i & 63;
        __builtin_nontemporal_store(emb[d * K + kfin[row]],
                                    &out_q[(size_t)(b * D + d) * HW + n0 + row]);
    }
}

extern "C" void kernel_launch(void* const* d_in, const int* in_sizes, int n_in,
                              void* d_out, int out_size, void* d_ws, size_t ws_size,
                              hipStream_t stream)
{
    const float* x   = (const float*)d_in[0];   // 4194304 floats
    const float* emb = (const float*)d_in[1];   // 32768 floats

    float* out_q   = (float*)d_out;                     // 4194304 floats
    float* out_idx = out_q + (size_t)64 * 64 * 1024;    // 65536 floats

    // 65536 rows / 64 rows-per-block = 1024 blocks of 256 threads
    // (4 code-quarters per row per block) -> 4 blocks/CU, 4 waves/SIMD.
    vq_argmin_kernel<<<1024, 256, 0, stream>>>(x, emb, out_q, out_idx);
}